// Round 3
// baseline (271.904 us; speedup 1.0000x reference)
//
#include <hip/hip_runtime.h>
#include <cstdint>
#include <cstddef>

// HardDetectionModule: per-element detect = is_depth_wise_max & is_local_max & is_not_edge
// batch: (B=2, C=512, H=192, W=256) float32, row-major.
// Output: same shape, int32 0/1 (reference returns bool -> harness reads int32).

namespace {

constexpr int Bn = 2;
constexpr int Cn = 512;
constexpr int Hn = 192;
constexpr int Wn = 256;
constexpr int CH = Hn * Wn;          // channel stride in elements (49152)
constexpr int NGROUPS = 16;          // 16 groups x 32 channels = 512

__global__ __launch_bounds__(64)
void hard_detect_kernel(const float* __restrict__ in, int* __restrict__ out) {
    const int tid = threadIdx.x;                 // 0..63
    const int j   = blockIdx.x * 64 + tid;       // 0..255
    const int i   = blockIdx.y;                  // 0..191
    const int b   = blockIdx.z;                  // 0..1

    // Per-thread group masks live in LDS (register arrays with runtime index
    // would spill to scratch). Layout [group][tid] -> stride-1 across lanes,
    // bank-conflict-free.
    __shared__ uint32_t smask[NGROUPS][64];
    __shared__ float    smaxv[NGROUPS][64];

    // element index of (b, c=0, i, j)
    const size_t base = ((size_t)b * Cn * Hn + (size_t)i) * Wn + (size_t)j;

    // ---- Pass 1: stream all 512 channels of this column.
    //  - running channel max M
    //  - zero the output (mandatory full write; doubles as init)
    //  - per-32-channel group: bitmask of "v == running max" (mask resets when
    //    a strictly larger value appears), plus the running max at group end.
    //    A group is valid iff its recorded max equals the final M; surviving
    //    bits then mark exactly the channels equal to the final M (ties exact).
    float M = -__builtin_inff();
    for (int w = 0; w < NGROUPS; ++w) {
        uint32_t m = 0u;
        #pragma unroll
        for (int k = 0; k < 32; ++k) {
            const size_t idx = base + (size_t)(w * 32 + k) * (size_t)CH;
            const float v = __builtin_nontemporal_load(&in[idx]);
            __builtin_nontemporal_store(0, &out[idx]);
            if (v > M) { M = v; m = (1u << k); }
            else if (v == M) { m |= (1u << k); }
        }
        smask[w][tid] = m;
        smaxv[w][tid] = M;
    }

    // Ensure the zero-stores complete before the sparse 1 overwrites below
    // (same thread, same addresses; global writes may complete out of order).
    asm volatile("s_waitcnt vmcnt(0)" ::: "memory");

    // ---- Pass 2: evaluate sparse candidates (channels where v == M).
    const bool has_u = (i > 0), has_d = (i < Hn - 1);
    const bool has_l = (j > 0), has_r = (j < Wn - 1);

    for (int w = 0; w < NGROUPS; ++w) {
        if (smaxv[w][tid] != M) continue;        // stale group (max grew later)
        uint32_t m = smask[w][tid];
        while (m) {
            const int k = __ffs(m) - 1;
            m &= (m - 1u);
            const int c = w * 32 + k;
            const size_t p = base + (size_t)c * (size_t)CH;
            const float v = M;                   // == in[p] by construction

            // 3x3 neighborhood; OOB -> 0 for the Hessian (zero-pad), and the
            // local-max test skips OOB neighbors (-inf pad semantics).
            const float nu  = has_u ? in[p - Wn] : 0.0f;
            const float nd  = has_d ? in[p + Wn] : 0.0f;
            const float nl  = has_l ? in[p - 1]  : 0.0f;
            const float nr  = has_r ? in[p + 1]  : 0.0f;
            const float nul = (has_u && has_l) ? in[p - Wn - 1] : 0.0f;
            const float nur = (has_u && has_r) ? in[p - Wn + 1] : 0.0f;
            const float ndl = (has_d && has_l) ? in[p + Wn - 1] : 0.0f;
            const float ndr = (has_d && has_r) ? in[p + Wn + 1] : 0.0f;

            const bool lm =
                (!has_u || v >= nu) && (!has_d || v >= nd) &&
                (!has_l || v >= nl) && (!has_r || v >= nr) &&
                (!(has_u && has_l) || v >= nul) &&
                (!(has_u && has_r) || v >= nur) &&
                (!(has_d && has_l) || v >= ndl) &&
                (!(has_d && has_r) || v >= ndr);

            if (lm) {
                // Hessian edge test, f32 ops matching numpy rounding.
                // __fmul_rn blocks fma contraction (det sign / ratio must
                // round exactly like separate-mul-then-sub).
                const float dii = (nu + nd) - 2.0f * v;
                const float djj = (nl + nr) - 2.0f * v;
                const float dij = 0.25f * (((nul - nur) - ndl) + ndr);
                const float det = __fmul_rn(dii, djj) - __fmul_rn(dij, dij);
                const float tr  = dii + djj;
                const float ratio = __fmul_rn(tr, tr) / det;   // inf/nan ok if det<=0
                if (det > 0.0f && ratio <= 7.2f) {             // 36/5
                    out[p] = 1;
                }
            }
        }
    }
}

} // namespace

extern "C" void kernel_launch(void* const* d_in, const int* in_sizes, int n_in,
                              void* d_out, int out_size, void* d_ws, size_t ws_size,
                              hipStream_t stream) {
    const float* in = (const float*)d_in[0];
    int* out = (int*)d_out;
    (void)in_sizes; (void)n_in; (void)out_size; (void)d_ws; (void)ws_size;

    dim3 grid(Wn / 64, Hn, Bn);   // 4 x 192 x 2 = 1536 one-wave blocks
    dim3 block(64);
    hipLaunchKernelGGL(hard_detect_kernel, grid, block, 0, stream, in, out);
}

// Round 5
// 68.196 us; speedup vs baseline: 3.9871x; 3.9871x over previous
//
#include <hip/hip_runtime.h>
#include <cstdint>
#include <cstddef>

// HardDetectionModule: per-element detect = is_depth_wise_max & is_local_max & is_not_edge
// batch: (B=2, C=512, H=192, W=256) float32, row-major.
// Output: same shape, int32 0/1 (reference returns bool -> harness reads int32).
//
// R3 -> R4: occupancy was 16.7% (1536 one-wave blocks), latency-bound at
// 1.1 TB/s. Now 512-thread blocks: 8 waves each own a 64-channel segment of
// the same 64 columns -> 12288 waves, ~5x memory parallelism.

namespace {

constexpr int Bn = 2;
constexpr int Cn = 512;
constexpr int Hn = 192;
constexpr int Wn = 256;
constexpr int CH  = Hn * Wn;         // channel stride in elements (49152)
constexpr int SEG = 8;               // wave-segments per column
constexpr int CPS = Cn / SEG;        // 64 channels per segment
constexpr int GPS = CPS / 32;        // 2 mask-groups per segment
constexpr int NGROUPS = SEG * GPS;   // 16 total

__global__ __launch_bounds__(512)
void hard_detect_kernel(const float* __restrict__ in, int* __restrict__ out) {
    const int tid = threadIdx.x & 63;        // column lane 0..63
    const int s   = threadIdx.x >> 6;        // segment (wave) 0..7
    const int j   = blockIdx.x * 64 + tid;   // 0..255
    const int i   = blockIdx.y;              // 0..191
    const int b   = blockIdx.z;              // 0..1

    // [group][lane] -> stride-1 across lanes, bank-conflict-free.
    __shared__ uint32_t smask[NGROUPS][64];
    __shared__ float    smaxv[NGROUPS][64];

    // element index of (b, c=0, i, j)
    const size_t base = ((size_t)b * Cn * Hn + (size_t)i) * Wn + (size_t)j;

    // ---- Pass 1: each wave streams its 64-channel segment of this column.
    //  - per-segment running max M
    //  - zero the output (mandatory full write; doubles as init)
    //  - per-32-channel group: bitmask of "v == running max" (mask resets when
    //    a strictly larger value appears), plus the running max at group end.
    float M = -__builtin_inff();
    for (int g = 0; g < GPS; ++g) {
        uint32_t m = 0u;
        #pragma unroll
        for (int k = 0; k < 32; ++k) {
            const int c = s * CPS + g * 32 + k;
            const size_t idx = base + (size_t)c * (size_t)CH;
            const float v = in[idx];                       // cached (L3 keeps input)
            __builtin_nontemporal_store(0, &out[idx]);     // output never re-read
            if (v > M) { M = v; m = (1u << k); }
            else if (v == M) { m |= (1u << k); }
        }
        smask[s * GPS + g][tid] = m;
        smaxv[s * GPS + g][tid] = M;
    }

    __syncthreads();

    // Global column max = max over the 8 segment-end running maxes.
    float Mg = smaxv[GPS - 1][tid];
    #pragma unroll
    for (int ss = 1; ss < SEG; ++ss)
        Mg = fmaxf(Mg, smaxv[ss * GPS + GPS - 1][tid]);

    // This thread's zero-stores must complete before its sparse 1-overwrites
    // (same addresses; global writes may complete out of order).
    asm volatile("s_waitcnt vmcnt(0)" ::: "memory");

    // ---- Pass 2: each wave evaluates candidates in its own segment
    // (channels where v == Mg). Expected ~1 candidate per column total.
    const bool has_u = (i > 0), has_d = (i < Hn - 1);
    const bool has_l = (j > 0), has_r = (j < Wn - 1);

    for (int g = 0; g < GPS; ++g) {
        if (smaxv[s * GPS + g][tid] != Mg) continue;  // stale group
        uint32_t m = smask[s * GPS + g][tid];
        while (m) {
            const int k = __ffs(m) - 1;
            m &= (m - 1u);
            const int c = s * CPS + g * 32 + k;
            const size_t p = base + (size_t)c * (size_t)CH;
            const float v = Mg;                   // == in[p] by construction

            // 3x3 neighborhood; OOB -> 0 for the Hessian (zero-pad), and the
            // local-max test skips OOB neighbors (-inf pad semantics).
            const float nu  = has_u ? in[p - Wn] : 0.0f;
            const float nd  = has_d ? in[p + Wn] : 0.0f;
            const float nl  = has_l ? in[p - 1]  : 0.0f;
            const float nr  = has_r ? in[p + 1]  : 0.0f;
            const float nul = (has_u && has_l) ? in[p - Wn - 1] : 0.0f;
            const float nur = (has_u && has_r) ? in[p - Wn + 1] : 0.0f;
            const float ndl = (has_d && has_l) ? in[p + Wn - 1] : 0.0f;
            const float ndr = (has_d && has_r) ? in[p + Wn + 1] : 0.0f;

            const bool lm =
                (!has_u || v >= nu) && (!has_d || v >= nd) &&
                (!has_l || v >= nl) && (!has_r || v >= nr) &&
                (!(has_u && has_l) || v >= nul) &&
                (!(has_u && has_r) || v >= nur) &&
                (!(has_d && has_l) || v >= ndl) &&
                (!(has_d && has_r) || v >= ndr);

            if (lm) {
                // Hessian edge test, f32 ops matching numpy rounding.
                // __fmul_rn blocks fma contraction (det sign / ratio must
                // round exactly like separate-mul-then-sub).
                const float dii = (nu + nd) - 2.0f * v;
                const float djj = (nl + nr) - 2.0f * v;
                const float dij = 0.25f * (((nul - nur) - ndl) + ndr);
                const float det = __fmul_rn(dii, djj) - __fmul_rn(dij, dij);
                const float tr  = dii + djj;
                const float ratio = __fmul_rn(tr, tr) / det;   // inf/nan ok if det<=0
                if (det > 0.0f && ratio <= 7.2f) {             // 36/5
                    out[p] = 1;
                }
            }
        }
    }
}

} // namespace

extern "C" void kernel_launch(void* const* d_in, const int* in_sizes, int n_in,
                              void* d_out, int out_size, void* d_ws, size_t ws_size,
                              hipStream_t stream) {
    const float* in = (const float*)d_in[0];
    int* out = (int*)d_out;
    (void)in_sizes; (void)n_in; (void)out_size; (void)d_ws; (void)ws_size;

    dim3 grid(Wn / 64, Hn, Bn);   // 4 x 192 x 2 = 1536 blocks x 8 waves
    dim3 block(512);
    hipLaunchKernelGGL(hard_detect_kernel, grid, block, 0, stream, in, out);
}

// Round 6
// 60.080 us; speedup vs baseline: 4.5257x; 1.1351x over previous
//
#include <hip/hip_runtime.h>
#include <cstdint>
#include <cstddef>

// HardDetectionModule: per-element detect = is_depth_wise_max & is_local_max & is_not_edge
// batch: (B=2, C=512, H=192, W=256) float32, row-major.
// Output: same shape, int32 0/1 (reference returns bool -> harness reads int32).
//
// R5 -> R6: 68.2 us at 4.7 TB/s effective (75% of copy ceiling). Now 2 columns
// per thread via float2 loads / 8B NT zero-stores: half the vmem instructions,
// 512B per wave memory op. Grid 768 blocks x 8 waves.

namespace {

constexpr int Bn = 2;
constexpr int Cn = 512;
constexpr int Hn = 192;
constexpr int Wn = 256;
constexpr int CH  = Hn * Wn;         // channel stride in elements (49152)
constexpr int SEG = 8;               // wave-segments per column
constexpr int CPS = Cn / SEG;        // 64 channels per segment
constexpr int GPS = CPS / 32;        // 2 mask-groups per segment
constexpr int NGROUPS = SEG * GPS;   // 16 total

__global__ __launch_bounds__(512)
void hard_detect_kernel(const float* __restrict__ in, int* __restrict__ out) {
    const int tid = threadIdx.x & 63;            // lane 0..63
    const int s   = threadIdx.x >> 6;            // segment (wave) 0..7
    const int j0  = blockIdx.x * 128 + tid * 2;  // even column of this lane's pair
    const int i   = blockIdx.y;                  // 0..191
    const int b   = blockIdx.z;                  // 0..1

    // [group][lane], 8B per lane -> 2-way LDS bank aliasing (free, m136).
    __shared__ uint2  smask[NGROUPS][64];
    __shared__ float2 smaxv[NGROUPS][64];

    // element index of (b, c=0, i, j0)
    const size_t base = ((size_t)b * Cn * Hn + (size_t)i) * Wn + (size_t)j0;

    // ---- Pass 1: each wave streams its 64-channel segment of 2 columns/lane.
    //  - per-column running max M0/M1
    //  - zero the output (mandatory full write; doubles as init), 8B NT stores
    //  - per-32-channel group: bitmask of "v == running max" per column (mask
    //    resets when a strictly larger value appears) + running max at group
    //    end. A group is valid iff its recorded max equals the final column
    //    max; surviving bits mark exactly the channels equal to it (ties exact).
    float M0 = -__builtin_inff(), M1 = -__builtin_inff();
    for (int g = 0; g < GPS; ++g) {
        uint32_t m0 = 0u, m1 = 0u;
        #pragma unroll
        for (int k = 0; k < 32; ++k) {
            const int c = s * CPS + g * 32 + k;
            const size_t idx = base + (size_t)c * (size_t)CH;
            const float2 v = *reinterpret_cast<const float2*>(&in[idx]);
            __builtin_nontemporal_store(0ULL,
                reinterpret_cast<unsigned long long*>(&out[idx]));
            if (v.x > M0) { M0 = v.x; m0 = (1u << k); }
            else if (v.x == M0) { m0 |= (1u << k); }
            if (v.y > M1) { M1 = v.y; m1 = (1u << k); }
            else if (v.y == M1) { m1 |= (1u << k); }
        }
        smask[s * GPS + g][tid] = make_uint2(m0, m1);
        smaxv[s * GPS + g][tid] = make_float2(M0, M1);
    }

    __syncthreads();

    // Global column maxes = max over the 8 segment-end running maxes.
    float Mg0 = smaxv[GPS - 1][tid].x;
    float Mg1 = smaxv[GPS - 1][tid].y;
    #pragma unroll
    for (int ss = 1; ss < SEG; ++ss) {
        Mg0 = fmaxf(Mg0, smaxv[ss * GPS + GPS - 1][tid].x);
        Mg1 = fmaxf(Mg1, smaxv[ss * GPS + GPS - 1][tid].y);
    }

    // This thread's zero-stores must complete before its sparse 1-overwrites
    // (same addresses; global writes may complete out of order).
    asm volatile("s_waitcnt vmcnt(0)" ::: "memory");

    // ---- Pass 2: each wave evaluates candidates in its own segment
    // (channels where v == column max). Expected ~1 candidate per column.
    const bool has_u = (i > 0), has_d = (i < Hn - 1);

    #pragma unroll
    for (int col = 0; col < 2; ++col) {
        const int j = j0 + col;
        const float Mg = col ? Mg1 : Mg0;
        const bool has_l = (j > 0), has_r = (j < Wn - 1);

        for (int g = 0; g < GPS; ++g) {
            const float2 sm = smaxv[s * GPS + g][tid];
            if ((col ? sm.y : sm.x) != Mg) continue;     // stale group
            const uint2 mm = smask[s * GPS + g][tid];
            uint32_t m = col ? mm.y : mm.x;
            while (m) {
                const int k = __ffs(m) - 1;
                m &= (m - 1u);
                const int c = s * CPS + g * 32 + k;
                const size_t p = base + (size_t)col + (size_t)c * (size_t)CH;
                const float v = Mg;                   // == in[p] by construction

                // 3x3 neighborhood; OOB -> 0 for the Hessian (zero-pad), and
                // the local-max test skips OOB neighbors (-inf pad semantics).
                const float nu  = has_u ? in[p - Wn] : 0.0f;
                const float nd  = has_d ? in[p + Wn] : 0.0f;
                const float nl  = has_l ? in[p - 1]  : 0.0f;
                const float nr  = has_r ? in[p + 1]  : 0.0f;
                const float nul = (has_u && has_l) ? in[p - Wn - 1] : 0.0f;
                const float nur = (has_u && has_r) ? in[p - Wn + 1] : 0.0f;
                const float ndl = (has_d && has_l) ? in[p + Wn - 1] : 0.0f;
                const float ndr = (has_d && has_r) ? in[p + Wn + 1] : 0.0f;

                const bool lm =
                    (!has_u || v >= nu) && (!has_d || v >= nd) &&
                    (!has_l || v >= nl) && (!has_r || v >= nr) &&
                    (!(has_u && has_l) || v >= nul) &&
                    (!(has_u && has_r) || v >= nur) &&
                    (!(has_d && has_l) || v >= ndl) &&
                    (!(has_d && has_r) || v >= ndr);

                if (lm) {
                    // Hessian edge test, f32 ops matching numpy rounding.
                    // __fmul_rn blocks fma contraction (det sign / ratio must
                    // round exactly like separate-mul-then-sub).
                    const float dii = (nu + nd) - 2.0f * v;
                    const float djj = (nl + nr) - 2.0f * v;
                    const float dij = 0.25f * (((nul - nur) - ndl) + ndr);
                    const float det = __fmul_rn(dii, djj) - __fmul_rn(dij, dij);
                    const float tr  = dii + djj;
                    const float ratio = __fmul_rn(tr, tr) / det; // inf/nan ok if det<=0
                    if (det > 0.0f && ratio <= 7.2f) {           // 36/5
                        out[p] = 1;
                    }
                }
            }
        }
    }
}

} // namespace

extern "C" void kernel_launch(void* const* d_in, const int* in_sizes, int n_in,
                              void* d_out, int out_size, void* d_ws, size_t ws_size,
                              hipStream_t stream) {
    const float* in = (const float*)d_in[0];
    int* out = (int*)d_out;
    (void)in_sizes; (void)n_in; (void)out_size; (void)d_ws; (void)ws_size;

    dim3 grid(Wn / 128, Hn, Bn);   // 2 x 192 x 2 = 768 blocks x 8 waves
    dim3 block(512);
    hipLaunchKernelGGL(hard_detect_kernel, grid, block, 0, stream, in, out);
}